// Round 13
// baseline (169.866 us; speedup 1.0000x reference)
//
#include <hip/hip_runtime.h>
#include <cstdint>
#include <cstddef>

#define S_DIM 1024
#define NPTS (S_DIM * S_DIM)
#define NLEV 16
#define TBL (1u << 19)
#define TMASK (TBL - 1u)
#define PRIME_Y 2654435761u

typedef float v4f __attribute__((ext_vector_type(4)));
typedef short v8s __attribute__((ext_vector_type(8)));
typedef float f2 __attribute__((ext_vector_type(2)));
typedef float f4 __attribute__((ext_vector_type(4)));

// may_alias access types for the encLDS bounce region (round-12 TBAA fix):
// bounce WRITES (2-dword) and b-frag/e-frag READS (4-dword) hit the same
// uint32_t LDS words with no barrier between them; may_alias pins the
// write->read dependency so the scheduler cannot reorder them (r11 failure).
typedef uint2 uint2_a __attribute__((may_alias));
typedef uint4 uint4_a __attribute__((may_alias));

// all 16 level resolutions; levels 0-9 are DENSE ((res+1)^2 <= 2^19), 10-15 hashed
static constexpr int RES_ALL[NLEV] = {16, 24, 36, 54, 81, 121, 182, 273,
                                      410, 615, 922, 1383, 2075, 3113, 4670, 7006};
// dense-level corner staging (r8-verified): distinct corner-x count per level
// and prefix offsets (float4 units). Sum = 477 (7632 B).
static constexpr int DCNT[10] = {6, 8, 11, 16, 23, 33, 48, 71, 105, 156};
static constexpr int DOFF[10] = {0, 6, 14, 25, 41, 64, 97, 145, 216, 321};
#define DTOT 477

// ---- split-bf16: x = hi + lo, both truncated bf16.  v_perm_b32 packs each
// output word in ONE op -- bit-identical to shift/or, 6 ops total. ----
__device__ __forceinline__ void split2(float a, float b, uint32_t& hi, uint32_t& lo) {
    uint32_t ua = __float_as_uint(a), ub = __float_as_uint(b);
    float la = a - __uint_as_float(ua & 0xFFFF0000u);
    float lb = b - __uint_as_float(ub & 0xFFFF0000u);
    hi = __builtin_amdgcn_perm(ub, ua, 0x07060302u);
    lo = __builtin_amdgcn_perm(__float_as_uint(lb), __float_as_uint(la), 0x07060302u);
}

// ---- hash-level gather/interp, two-stage so gathers can issue early --------
struct HashLvl {
    f2 f00, f01, f10, f11;
    float wx, wy;
};
static __device__ __forceinline__ HashLvl hash_load(float x, float y, int res,
                                                    const float* __restrict__ tb) {
    const float fr = (float)res;
    const float px = x * fr, py = y * fr;
    const float fx = floorf(px), fy = floorf(py);
    HashLvl h;
    h.wx = px - fx;
    h.wy = py - fy;
    const unsigned a = (unsigned)(int)fx, b = (unsigned)(int)fy;
    const unsigned hb0 = b * PRIME_Y;
    const unsigned hb1 = hb0 + PRIME_Y;          // == (b+1)*PRIME mod 2^32
    const int i00 = (int)((a ^ hb0) & TMASK);
    const int i01 = (int)((a ^ hb1) & TMASK);
    const int i10 = (int)(((a + 1u) ^ hb0) & TMASK);
    const int i11 = (int)(((a + 1u) ^ hb1) & TMASK);
    h.f00 = *(const f2*)(tb + 2 * (size_t)i00);
    h.f01 = *(const f2*)(tb + 2 * (size_t)i01);
    h.f10 = *(const f2*)(tb + 2 * (size_t)i10);
    h.f11 = *(const f2*)(tb + 2 * (size_t)i11);
    return h;
}
static __device__ __forceinline__ f2 hash_interp(const HashLvl& h) {
    const float omx = 1.f - h.wx, omy = 1.f - h.wy;
    const float w00 = omx * omy, w01 = omx * h.wy;
    const float w10 = h.wx * omy, w11 = h.wx * h.wy;
    return h.f00 * w00 + h.f01 * w01 + h.f10 * w10 + h.f11 * w11;
}

// ---- dense-level interp from the LDS corner stage (packed f32) -------------
static __device__ __forceinline__ f2 dense_interp(const f4* __restrict__ stage,
                                                  int l, f2 p, float p00x) {
    const float fr = (float)RES_ALL[l];
    const float px = p.x * fr, py = p.y * fr;
    const float fx = floorf(px), fy = floorf(py);
    const float wx = px - fx, wy = py - fy;
    const int xi = (int)fx - (int)floorf(p00x * fr);
    const f4 c0 = stage[DOFF[l] + xi];       // f00 | f01
    const f4 c1 = stage[DOFF[l] + xi + 1];   // f10 | f11
    const float omx = 1.f - wx, omy = 1.f - wy;
    const float w00 = omx * omy, w01 = omx * wy;
    const float w10 = wx * omy,  w11 = wx * wy;
    return c0.xy * w00 + c0.zw * w01 + c1.xy * w10 + c1.zw * w11;
}

// ============================================================================
// Main kernel — SINGLE DISPATCH (round-13).  The separate prep_weights kernel
// is gone: each block recomputes the bf16 hi/lo weight fragments it needs
// directly from W0/W1 global (16+24 KB, L2/L3-resident for all blocks).
//   - W1 frags: thread tid computes frag-units tid and tid+256 (8 W1 loads +
//     4 split2 each) into w1LDS[u] (hi) / w1LDS[512+u] (lo) — bit-identical
//     index algebra to the old prep_weights b!=0 branch.
//   - W0 frags: each lane computes its 8 uint4 (32 loads + 16 split2) in the
//     slot where the ws loads used to sit.
//   Cost ~200 instrs/thread once per block (~+2-3 us on this kernel); saves
//   the prep dispatch + inter-kernel gap from the measured total (~80 us of
//   every round's bench total was non-main-kernel time).
// Everything else is byte-for-byte round-12 (verified, absmax 9.54e-7):
// phase 0/1 (stage loads -> hash gathers in flight -> stage writes -> dense
// interp), TBAA-safe bounce (may_alias), unroll-2 + e-frag prefetch phase 2,
// LDS map enc 36864 + w1/stage 16384 = 53248 -> 3 blocks/CU.
// Spill tripwire: WRITE_SIZE > 30 MB means the reg budget failed.
// ============================================================================
__global__ __launch_bounds__(256, 3) void ngp_mfma(
    const float* __restrict__ xy,
    const float* __restrict__ tables,
    const float* __restrict__ W0,
    const float* __restrict__ W1,
    const float* __restrict__ W2,
    float* __restrict__ out)
{
    __shared__ alignas(16) uint32_t encLDS[256 * 36];        // 36864 B
    __shared__ alignas(16) uint4 w1LDS[1024];                // 16384 B

    const int tid = threadIdx.x;
    const int lane = tid & 63;
    const int wave = tid >> 6;
    const int m = lane & 15, q = lane >> 4;
    const int blockBase = blockIdx.x * 256;

    const float2 p00 = ((const float2*)xy)[blockBase];   // block's first point
    const f2 p = *((const f2*)(xy + 2 * (size_t)(blockBase + tid)));

    // ---------------- Phase 0a: stage LOADS (issue first = oldest) ----------
    f4 sv0, sv1;
    int su1valid = (tid + 256 < DTOT);
    {
        #pragma unroll
        for (int it = 0; it < 2; ++it) {
            const int u = tid + it * 256;
            if (it == 0 || su1valid) {
                int l = 0;
                #pragma unroll
                for (int k = 1; k < 10; ++k) l += (u >= DOFF[k]);
                const int r  = RES_ALL[l];
                const float fr = (float)r;
                const int X0 = (int)floorf(p00.x * fr);
                const int x  = min(X0 + (u - DOFF[l]), r);
                const int y0 = (int)floorf(p00.y * fr);
                const int st = r + 1;
                const float* tb = tables + (size_t)l * (size_t)(TBL * 2u);
                const float2 f0 = *(const float2*)(tb + 2 * (size_t)(x + y0 * st));
                const float2 f1 = *(const float2*)(tb + 2 * (size_t)(x + y0 * st + st));
                if (it == 0) sv0 = (f4){f0.x, f0.y, f1.x, f1.y};
                else         sv1 = (f4){f0.x, f0.y, f1.x, f1.y};
            }
        }
    }

    // ---------------- Phase 0b: issue ALL hash gathers (levels 10-15) ------
    HashLvl hl[6];
    #pragma unroll
    for (int i = 0; i < 6; ++i)
        hl[i] = hash_load(p.x, p.y, RES_ALL[10 + i],
                          tables + (size_t)(10 + i) * (size_t)(TBL * 2u));

    // ---------------- Phase 0c: stage WRITES (wait only on own loads) ------
    {
        f4* stage = (f4*)w1LDS;
        stage[tid] = sv0;
        if (su1valid) stage[tid + 256] = sv1;
    }
    __syncthreads();   // stage visible to all waves

    // ---------------- Phase 1: encode own point ----------------
    {
        const f4* stage = (const f4*)w1LDS;
        uint32_t* row = encLDS + tid * 36;

        #pragma unroll
        for (int g = 0; g < 2; ++g) {
            uint32_t hi[4], lo[4];
            #pragma unroll
            for (int i = 0; i < 4; ++i) {
                const f2 e = dense_interp(stage, g * 4 + i, p, p00.x);
                split2(e.x, e.y, hi[i], lo[i]);
            }
            *((uint4_a*)(row + 4 * g))      = make_uint4(hi[0], hi[1], hi[2], hi[3]);
            *((uint4_a*)(row + 16 + 4 * g)) = make_uint4(lo[0], lo[1], lo[2], lo[3]);
        }
        {
            uint32_t hi[4], lo[4];
            #pragma unroll
            for (int i = 0; i < 2; ++i) {
                const f2 e = dense_interp(stage, 8 + i, p, p00.x);
                split2(e.x, e.y, hi[i], lo[i]);
            }
            #pragma unroll
            for (int i = 0; i < 2; ++i) {
                const f2 e = hash_interp(hl[i]);
                split2(e.x, e.y, hi[2 + i], lo[2 + i]);
            }
            *((uint4_a*)(row + 8))      = make_uint4(hi[0], hi[1], hi[2], hi[3]);
            *((uint4_a*)(row + 16 + 8)) = make_uint4(lo[0], lo[1], lo[2], lo[3]);
        }
        {
            uint32_t hi[4], lo[4];
            #pragma unroll
            for (int i = 0; i < 4; ++i) {
                const f2 e = hash_interp(hl[2 + i]);
                split2(e.x, e.y, hi[i], lo[i]);
            }
            *((uint4_a*)(row + 12))      = make_uint4(hi[0], hi[1], hi[2], hi[3]);
            *((uint4_a*)(row + 16 + 12)) = make_uint4(lo[0], lo[1], lo[2], lo[3]);
        }
    }

    __syncthreads();   // all waves done reading stage -> safe to overwrite

    // ---------------- compute W1 frags -> LDS (replaces prep_weights) ------
    // thread tid builds frag-units u = tid and tid+256: unit u -> frag=u>>6,
    // l2=u&63; nt=frag>>1, ks=frag&1; n=nt*16+(l2&15); k0=ks*32+(l2>>4)*8+2d.
    // Bit-identical to the old prep_weights b!=0 branch.
    #pragma unroll
    for (int r = 0; r < 2; ++r) {
        const int u = tid + 256 * r;          // in [0,512)
        const int frag = u >> 6, l2 = u & 63;
        const int nn = (frag >> 1) * 16 + (l2 & 15);
        const int kq = (frag & 1) * 32 + (l2 >> 4) * 8;
        uint32_t hi[4], lo[4];
        #pragma unroll
        for (int d = 0; d < 4; ++d) {
            const int k0 = kq + 2 * d;
            split2(W1[k0 * 64 + nn], W1[(k0 + 1) * 64 + nn], hi[d], lo[d]);
        }
        w1LDS[u]       = make_uint4(hi[0], hi[1], hi[2], hi[3]);
        w1LDS[512 + u] = make_uint4(lo[0], lo[1], lo[2], lo[3]);
    }

    __syncthreads();   // w1LDS visible

    __builtin_amdgcn_sched_barrier(0);

    // ---------------- W0 fragments: computed per-lane into registers -------
    // lane (m,q), tile t: n=t*16+m, k0=q*8+2d — identical to old prep b==0.
    v8s w0h[4], w0l[4];
    #pragma unroll
    for (int t = 0; t < 4; ++t) {
        const int nn = t * 16 + m;
        uint32_t hi[4], lo[4];
        #pragma unroll
        for (int d = 0; d < 4; ++d) {
            const int k0 = q * 8 + 2 * d;
            split2(W0[k0 * 64 + nn], W0[(k0 + 1) * 64 + nn], hi[d], lo[d]);
        }
        w0h[t] = __builtin_bit_cast(v8s, make_uint4(hi[0], hi[1], hi[2], hi[3]));
        w0l[t] = __builtin_bit_cast(v8s, make_uint4(lo[0], lo[1], lo[2], lo[3]));
    }

    // ---- e-frags of tile 0, preloaded ----
    v8s eHc, eLc;
    {
        const uint32_t* r0 = encLDS + (wave * 64 + m) * 36;
        eHc = __builtin_bit_cast(v8s, *((const uint4_a*)(r0 + q * 4)));
        eLc = __builtin_bit_cast(v8s, *((const uint4_a*)(r0 + 16 + q * 4)));
    }

    // ---------------- Phase 2: 4 M-tiles, unroll 2, e-frag prefetch --------
    #pragma unroll 2
    for (int t = 0; t < 4; ++t) {
        // launder a zero through opaque asm so LICM cannot hoist the
        // per-tile w1LDS reads / W2 global reads out of this loop.
        int tOff = 0;
        asm volatile("" : "+v"(tOff));

        // this tile's enc row for lane's m — also the h0 bounce row.
        uint32_t* hrow = encLDS + (wave * 64 + t * 16 + m) * 36;

        // ---- PREFETCH next tile's e-frags (rows +16: disjoint from this
        // tile's bounce writes — value-safe under any reordering) ----
        v8s eHn = eHc, eLn = eLc;
        if (t < 3) {
            const uint32_t* rn = hrow + 16 * 36;
            eHn = __builtin_bit_cast(v8s, *((const uint4_a*)(rn + q * 4)));
            eLn = __builtin_bit_cast(v8s, *((const uint4_a*)(rn + 16 + q * 4)));
        }

        // ---- L0: D0[n][p] = W0^T x enc^T, 3-term split ----
        v4f acc0[4];
        #pragma unroll
        for (int nt = 0; nt < 4; ++nt) {
            v4f c = {0.f, 0.f, 0.f, 0.f};
            c = __builtin_amdgcn_mfma_f32_16x16x32_bf16(w0l[nt], eHc, c, 0, 0, 0);
            c = __builtin_amdgcn_mfma_f32_16x16x32_bf16(w0h[nt], eLc, c, 0, 0, 0);
            c = __builtin_amdgcn_mfma_f32_16x16x32_bf16(w0h[nt], eHc, c, 0, 0, 0);
            acc0[nt] = c;
        }

        v4f acc1[4];
        #pragma unroll
        for (int nt = 0; nt < 4; ++nt) acc1[nt] = (v4f){0.f, 0.f, 0.f, 0.f};

        // ---- L1 in two ks-halves, bouncing through this tile's enc rows ----
        #pragma unroll
        for (int ks = 0; ks < 2; ++ks) {
            #pragma unroll
            for (int nh = 0; nh < 2; ++nh) {
                const int nt = ks * 2 + nh;
                const float r0 = fmaxf(acc0[nt][0], 0.f), r1 = fmaxf(acc0[nt][1], 0.f);
                const float r2 = fmaxf(acc0[nt][2], 0.f), r3 = fmaxf(acc0[nt][3], 0.f);
                uint32_t h0w, l0w, h1w, l1w;
                split2(r0, r1, h0w, l0w);
                split2(r2, r3, h1w, l1w);
                *((uint2_a*)(hrow + nh * 8 + q * 2))      = make_uint2(h0w, h1w);
                *((uint2_a*)(hrow + 16 + nh * 8 + q * 2)) = make_uint2(l0w, l1w);
            }
            const v8s bH = __builtin_bit_cast(v8s, *((const uint4_a*)(hrow + q * 4)));
            const v8s bL = __builtin_bit_cast(v8s, *((const uint4_a*)(hrow + 16 + q * 4)));

            #pragma unroll
            for (int nt = 0; nt < 4; ++nt) {
                const v8s a_h = __builtin_bit_cast(v8s, w1LDS[tOff + (nt * 2 + ks) * 64 + lane]);
                const v8s a_l = __builtin_bit_cast(v8s, w1LDS[tOff + 512 + (nt * 2 + ks) * 64 + lane]);
                v4f c = acc1[nt];
                c = __builtin_amdgcn_mfma_f32_16x16x32_bf16(a_l, bH, c, 0, 0, 0);
                c = __builtin_amdgcn_mfma_f32_16x16x32_bf16(a_h, bL, c, 0, 0, 0);
                c = __builtin_amdgcn_mfma_f32_16x16x32_bf16(a_h, bH, c, 0, 0, 0);
                acc1[nt] = c;
            }
        }

        // ---- L2 (64->3) in VALU: W2 direct from global (768 B, L1-hot) ----
        float o0 = 0.f, o1 = 0.f, o2 = 0.f;
        #pragma unroll
        for (int nt = 0; nt < 4; ++nt) {
            const int n0 = nt * 16 + q * 4;
            const float4 g0 = *((const float4*)(W2 + n0 * 3 + tOff));
            const float4 g1 = *((const float4*)(W2 + n0 * 3 + tOff + 4));
            const float4 g2 = *((const float4*)(W2 + n0 * 3 + tOff + 8));
            const float h0r = fmaxf(acc1[nt][0], 0.f), h1r = fmaxf(acc1[nt][1], 0.f);
            const float h2r = fmaxf(acc1[nt][2], 0.f), h3r = fmaxf(acc1[nt][3], 0.f);
            o0 = fmaf(h0r, g0.x, fmaf(h1r, g0.w, fmaf(h2r, g1.z, fmaf(h3r, g2.y, o0))));
            o1 = fmaf(h0r, g0.y, fmaf(h1r, g1.x, fmaf(h2r, g1.w, fmaf(h3r, g2.z, o1))));
            o2 = fmaf(h0r, g0.z, fmaf(h1r, g1.y, fmaf(h2r, g2.x, fmaf(h3r, g2.w, o2))));
        }
        o0 += __shfl_xor(o0, 16); o0 += __shfl_xor(o0, 32);
        o1 += __shfl_xor(o1, 16); o1 += __shfl_xor(o1, 32);
        o2 += __shfl_xor(o2, 16); o2 += __shfl_xor(o2, 32);

        if (lane < 16) {
            const int p2 = blockBase + wave * 64 + t * 16 + lane;
            out[p2] = o0;
            out[NPTS + p2] = o1;
            out[2 * NPTS + p2] = o2;
        }

        // rotate prefetched e-frags into place for the next tile
        eHc = eHn;
        eLc = eLn;
    }
}

extern "C" void kernel_launch(void* const* d_in, const int* in_sizes, int n_in,
                              void* d_out, int out_size, void* d_ws, size_t ws_size,
                              hipStream_t stream) {
    const float* xy     = (const float*)d_in[0];
    const float* tables = (const float*)d_in[1];
    const float* W0     = (const float*)d_in[2];
    const float* W1     = (const float*)d_in[3];
    const float* W2     = (const float*)d_in[4];
    float* out = (float*)d_out;
    (void)d_ws; (void)ws_size;   // workspace no longer needed

    hipLaunchKernelGGL(ngp_mfma, dim3(NPTS / 256), dim3(256), 0, stream,
                       xy, tables, W0, W1, W2, out);
}

// Round 14
// 167.441 us; speedup vs baseline: 1.0145x; 1.0145x over previous
//
#include <hip/hip_runtime.h>
#include <cstdint>
#include <cstddef>

#define S_DIM 1024
#define NPTS (S_DIM * S_DIM)
#define NLEV 16
#define TBL (1u << 19)
#define TMASK (TBL - 1u)
#define PRIME_Y 2654435761u

typedef float v4f __attribute__((ext_vector_type(4)));
typedef short v8s __attribute__((ext_vector_type(8)));
typedef float f2 __attribute__((ext_vector_type(2)));
typedef float f4 __attribute__((ext_vector_type(4)));

// may_alias access types for the encLDS bounce region (round-12 TBAA fix):
// bounce WRITES (2-dword) and b-frag/e-frag READS (4-dword) hit the same
// uint32_t LDS words with no barrier between them; may_alias pins the
// write->read dependency so the scheduler cannot reorder them (r11 failure).
typedef uint2 uint2_a __attribute__((may_alias));
typedef uint4 uint4_a __attribute__((may_alias));

// all 16 level resolutions; levels 0-9 are DENSE ((res+1)^2 <= 2^19), 10-15 hashed
static constexpr int RES_ALL[NLEV] = {16, 24, 36, 54, 81, 121, 182, 273,
                                      410, 615, 922, 1383, 2075, 3113, 4670, 7006};
// dense-level corner staging (r8-verified): distinct corner-x count per level
// and prefix offsets (float4 units). Sum = 477 (7632 B).
static constexpr int DCNT[10] = {6, 8, 11, 16, 23, 33, 48, 71, 105, 156};
static constexpr int DOFF[10] = {0, 6, 14, 25, 41, 64, 97, 145, 216, 321};
#define DTOT 477

// ---- split-bf16: x = hi + lo, both truncated bf16.  v_perm_b32 packs each
// output word in ONE op -- bit-identical to shift/or, 6 ops total. ----
__device__ __forceinline__ void split2(float a, float b, uint32_t& hi, uint32_t& lo) {
    uint32_t ua = __float_as_uint(a), ub = __float_as_uint(b);
    float la = a - __uint_as_float(ua & 0xFFFF0000u);
    float lb = b - __uint_as_float(ub & 0xFFFF0000u);
    hi = __builtin_amdgcn_perm(ub, ua, 0x07060302u);
    lo = __builtin_amdgcn_perm(__float_as_uint(lb), __float_as_uint(la), 0x07060302u);
}

// ============================================================================
// Pre-pass (3 blocks): bf16 hi/lo A-fragments of W0^T and W1^T into d_ws.
// ws as uint4: [0,256) W0hi | [256,512) W0lo | [512,1024) W1hi | [1024,1536) W1lo
// (r13 lesson: fusing this into the main kernel saves NO measured time — the
// ~82 us total-vs-main gap is harness reset machinery, not dispatch overhead —
// and costs ~3 us of per-block recompute.  Two dispatches is the optimum.)
// ============================================================================
__global__ __launch_bounds__(256) void prep_weights(const float* __restrict__ W0,
                                                    const float* __restrict__ W1,
                                                    uint4* __restrict__ ws) {
    const int tid = threadIdx.x;          // 0..255
    const int b = blockIdx.x;             // 0..2

    if (b == 0) {   // W0^T: 4 n-tiles, 1 k-step. unit = tid.
        const int lane = tid & 63;
        const int m = lane & 15, q = lane >> 4;
        const int tile = tid >> 6;
        const int n = tile * 16 + m;
        uint32_t hi[4], lo[4];
        #pragma unroll
        for (int d = 0; d < 4; ++d) {
            const int k0 = q * 8 + 2 * d;
            split2(W0[k0 * 64 + n], W0[(k0 + 1) * 64 + n], hi[d], lo[d]);
        }
        ws[tid]       = make_uint4(hi[0], hi[1], hi[2], hi[3]);
        ws[256 + tid] = make_uint4(lo[0], lo[1], lo[2], lo[3]);
    } else {        // W1^T: 8 frags (nt*2+ks) x 64 lanes; unit in [0,512)
        const int unit = tid + (b - 1) * 256;
        const int l2 = unit & 63, frag = unit >> 6;
        const int nt = frag >> 1, ks = frag & 1;
        const int mm = l2 & 15, qq = l2 >> 4;
        const int n = nt * 16 + mm;
        uint32_t hi[4], lo[4];
        #pragma unroll
        for (int d = 0; d < 4; ++d) {
            const int k0 = ks * 32 + qq * 8 + 2 * d;
            split2(W1[k0 * 64 + n], W1[(k0 + 1) * 64 + n], hi[d], lo[d]);
        }
        ws[512 + unit]  = make_uint4(hi[0], hi[1], hi[2], hi[3]);
        ws[1024 + unit] = make_uint4(lo[0], lo[1], lo[2], lo[3]);
    }
}

// ---- hash-level gather/interp, two-stage so gathers can issue early --------
struct HashLvl {
    f2 f00, f01, f10, f11;
    float wx, wy;
};
static __device__ __forceinline__ HashLvl hash_load(float x, float y, int res,
                                                    const float* __restrict__ tb) {
    const float fr = (float)res;
    const float px = x * fr, py = y * fr;
    const float fx = floorf(px), fy = floorf(py);
    HashLvl h;
    h.wx = px - fx;
    h.wy = py - fy;
    const unsigned a = (unsigned)(int)fx, b = (unsigned)(int)fy;
    const unsigned hb0 = b * PRIME_Y;
    const unsigned hb1 = hb0 + PRIME_Y;          // == (b+1)*PRIME mod 2^32
    const int i00 = (int)((a ^ hb0) & TMASK);
    const int i01 = (int)((a ^ hb1) & TMASK);
    const int i10 = (int)(((a + 1u) ^ hb0) & TMASK);
    const int i11 = (int)(((a + 1u) ^ hb1) & TMASK);
    h.f00 = *(const f2*)(tb + 2 * (size_t)i00);
    h.f01 = *(const f2*)(tb + 2 * (size_t)i01);
    h.f10 = *(const f2*)(tb + 2 * (size_t)i10);
    h.f11 = *(const f2*)(tb + 2 * (size_t)i11);
    return h;
}
static __device__ __forceinline__ f2 hash_interp(const HashLvl& h) {
    const float omx = 1.f - h.wx, omy = 1.f - h.wy;
    const float w00 = omx * omy, w01 = omx * h.wy;
    const float w10 = h.wx * omy, w11 = h.wx * h.wy;
    return h.f00 * w00 + h.f01 * w01 + h.f10 * w10 + h.f11 * w11;
}

// ---- dense-level interp from the LDS corner stage (packed f32) -------------
static __device__ __forceinline__ f2 dense_interp(const f4* __restrict__ stage,
                                                  int l, f2 p, float p00x) {
    const float fr = (float)RES_ALL[l];
    const float px = p.x * fr, py = p.y * fr;
    const float fx = floorf(px), fy = floorf(py);
    const float wx = px - fx, wy = py - fy;
    const int xi = (int)fx - (int)floorf(p00x * fr);
    const f4 c0 = stage[DOFF[l] + xi];       // f00 | f01
    const f4 c1 = stage[DOFF[l] + xi + 1];   // f10 | f11
    const float omx = 1.f - wx, omy = 1.f - wy;
    const float w00 = omx * omy, w01 = omx * wy;
    const float w10 = wx * omy,  w11 = wx * wy;
    return c0.xy * w00 + c0.zw * w01 + c1.xy * w10 + c1.zw * w11;
}

// ============================================================================
// Main kernel — round-12 configuration, the measured optimum (167.2 us total,
// 84.5 us main, absmax 9.54e-7).  Structure:
//   Phase 0: dense-corner stage loads -> ALL hash gathers issued (stay in
//            flight through writes/barrier/dense work) -> stage writes.
//   Phase 1: encode own point (10 dense levels from LDS stage, 6 hashed).
//   Phase 2: 4 M-tiles, unroll 2, e-frag prefetch; L0 MFMA (W0 in regs),
//            TBAA-safe h0 bounce through own enc rows (may_alias), L1 MFMA
//            (W1 frags from LDS), L2 (64->3) in VALU + shfl_xor reduce.
// LDS: enc 36864 + w1/stage 16384 = 53248 = 26 x 2048 -> 3 blocks/CU.
// Spill tripwire: WRITE_SIZE > 30 MB means the reg budget failed.
// ============================================================================
__global__ __launch_bounds__(256, 3) void ngp_mfma(
    const float* __restrict__ xy,
    const float* __restrict__ tables,
    const float* __restrict__ W2,
    const uint4* __restrict__ ws,
    float* __restrict__ out)
{
    __shared__ alignas(16) uint32_t encLDS[256 * 36];        // 36864 B
    __shared__ alignas(16) uint4 w1LDS[1024];                // 16384 B

    const int tid = threadIdx.x;
    const int lane = tid & 63;
    const int wave = tid >> 6;
    const int m = lane & 15, q = lane >> 4;
    const int blockBase = blockIdx.x * 256;

    const float2 p00 = ((const float2*)xy)[blockBase];   // block's first point
    const f2 p = *((const f2*)(xy + 2 * (size_t)(blockBase + tid)));

    // ---------------- Phase 0a: stage LOADS (issue first = oldest) ----------
    f4 sv0, sv1;
    int su1valid = (tid + 256 < DTOT);
    {
        #pragma unroll
        for (int it = 0; it < 2; ++it) {
            const int u = tid + it * 256;
            if (it == 0 || su1valid) {
                int l = 0;
                #pragma unroll
                for (int k = 1; k < 10; ++k) l += (u >= DOFF[k]);
                const int r  = RES_ALL[l];
                const float fr = (float)r;
                const int X0 = (int)floorf(p00.x * fr);
                const int x  = min(X0 + (u - DOFF[l]), r);
                const int y0 = (int)floorf(p00.y * fr);
                const int st = r + 1;
                const float* tb = tables + (size_t)l * (size_t)(TBL * 2u);
                const float2 f0 = *(const float2*)(tb + 2 * (size_t)(x + y0 * st));
                const float2 f1 = *(const float2*)(tb + 2 * (size_t)(x + y0 * st + st));
                if (it == 0) sv0 = (f4){f0.x, f0.y, f1.x, f1.y};
                else         sv1 = (f4){f0.x, f0.y, f1.x, f1.y};
            }
        }
    }

    // ---------------- Phase 0b: issue ALL hash gathers (levels 10-15) ------
    HashLvl hl[6];
    #pragma unroll
    for (int i = 0; i < 6; ++i)
        hl[i] = hash_load(p.x, p.y, RES_ALL[10 + i],
                          tables + (size_t)(10 + i) * (size_t)(TBL * 2u));

    // ---------------- Phase 0c: stage WRITES (wait only on own loads) ------
    {
        f4* stage = (f4*)w1LDS;
        stage[tid] = sv0;
        if (su1valid) stage[tid + 256] = sv1;
    }
    __syncthreads();   // stage visible to all waves

    // ---------------- Phase 1: encode own point ----------------
    {
        const f4* stage = (const f4*)w1LDS;
        uint32_t* row = encLDS + tid * 36;

        #pragma unroll
        for (int g = 0; g < 2; ++g) {
            uint32_t hi[4], lo[4];
            #pragma unroll
            for (int i = 0; i < 4; ++i) {
                const f2 e = dense_interp(stage, g * 4 + i, p, p00.x);
                split2(e.x, e.y, hi[i], lo[i]);
            }
            *((uint4_a*)(row + 4 * g))      = make_uint4(hi[0], hi[1], hi[2], hi[3]);
            *((uint4_a*)(row + 16 + 4 * g)) = make_uint4(lo[0], lo[1], lo[2], lo[3]);
        }
        {
            uint32_t hi[4], lo[4];
            #pragma unroll
            for (int i = 0; i < 2; ++i) {
                const f2 e = dense_interp(stage, 8 + i, p, p00.x);
                split2(e.x, e.y, hi[i], lo[i]);
            }
            #pragma unroll
            for (int i = 0; i < 2; ++i) {
                const f2 e = hash_interp(hl[i]);
                split2(e.x, e.y, hi[2 + i], lo[2 + i]);
            }
            *((uint4_a*)(row + 8))      = make_uint4(hi[0], hi[1], hi[2], hi[3]);
            *((uint4_a*)(row + 16 + 8)) = make_uint4(lo[0], lo[1], lo[2], lo[3]);
        }
        {
            uint32_t hi[4], lo[4];
            #pragma unroll
            for (int i = 0; i < 4; ++i) {
                const f2 e = hash_interp(hl[2 + i]);
                split2(e.x, e.y, hi[i], lo[i]);
            }
            *((uint4_a*)(row + 12))      = make_uint4(hi[0], hi[1], hi[2], hi[3]);
            *((uint4_a*)(row + 16 + 12)) = make_uint4(lo[0], lo[1], lo[2], lo[3]);
        }
    }

    __syncthreads();   // all waves done reading stage -> safe to overwrite

    // ---------------- stage W1 frags global->LDS (overwrites stage) --------
    #pragma unroll
    for (int i = 0; i < 4; ++i) w1LDS[tid + 256 * i] = ws[512 + tid + 256 * i];

    __syncthreads();   // w1LDS visible

    __builtin_amdgcn_sched_barrier(0);

    // ---------------- W0 fragments: registers, reused by all 4 tiles -------
    v8s w0h[4], w0l[4];
    #pragma unroll
    for (int t = 0; t < 4; ++t) {
        w0h[t] = __builtin_bit_cast(v8s, ws[t * 64 + lane]);
        w0l[t] = __builtin_bit_cast(v8s, ws[256 + t * 64 + lane]);
    }

    // ---- e-frags of tile 0, preloaded ----
    v8s eHc, eLc;
    {
        const uint32_t* r0 = encLDS + (wave * 64 + m) * 36;
        eHc = __builtin_bit_cast(v8s, *((const uint4_a*)(r0 + q * 4)));
        eLc = __builtin_bit_cast(v8s, *((const uint4_a*)(r0 + 16 + q * 4)));
    }

    // ---------------- Phase 2: 4 M-tiles, unroll 2, e-frag prefetch --------
    #pragma unroll 2
    for (int t = 0; t < 4; ++t) {
        // launder a zero through opaque asm so LICM cannot hoist the
        // per-tile w1LDS reads / W2 global reads out of this loop.
        int tOff = 0;
        asm volatile("" : "+v"(tOff));

        // this tile's enc row for lane's m — also the h0 bounce row.
        uint32_t* hrow = encLDS + (wave * 64 + t * 16 + m) * 36;

        // ---- PREFETCH next tile's e-frags (rows +16: disjoint from this
        // tile's bounce writes — value-safe under any reordering) ----
        v8s eHn = eHc, eLn = eLc;
        if (t < 3) {
            const uint32_t* rn = hrow + 16 * 36;
            eHn = __builtin_bit_cast(v8s, *((const uint4_a*)(rn + q * 4)));
            eLn = __builtin_bit_cast(v8s, *((const uint4_a*)(rn + 16 + q * 4)));
        }

        // ---- L0: D0[n][p] = W0^T x enc^T, 3-term split ----
        v4f acc0[4];
        #pragma unroll
        for (int nt = 0; nt < 4; ++nt) {
            v4f c = {0.f, 0.f, 0.f, 0.f};
            c = __builtin_amdgcn_mfma_f32_16x16x32_bf16(w0l[nt], eHc, c, 0, 0, 0);
            c = __builtin_amdgcn_mfma_f32_16x16x32_bf16(w0h[nt], eLc, c, 0, 0, 0);
            c = __builtin_amdgcn_mfma_f32_16x16x32_bf16(w0h[nt], eHc, c, 0, 0, 0);
            acc0[nt] = c;
        }

        v4f acc1[4];
        #pragma unroll
        for (int nt = 0; nt < 4; ++nt) acc1[nt] = (v4f){0.f, 0.f, 0.f, 0.f};

        // ---- L1 in two ks-halves, bouncing through this tile's enc rows ----
        #pragma unroll
        for (int ks = 0; ks < 2; ++ks) {
            #pragma unroll
            for (int nh = 0; nh < 2; ++nh) {
                const int nt = ks * 2 + nh;
                const float r0 = fmaxf(acc0[nt][0], 0.f), r1 = fmaxf(acc0[nt][1], 0.f);
                const float r2 = fmaxf(acc0[nt][2], 0.f), r3 = fmaxf(acc0[nt][3], 0.f);
                uint32_t h0w, l0w, h1w, l1w;
                split2(r0, r1, h0w, l0w);
                split2(r2, r3, h1w, l1w);
                *((uint2_a*)(hrow + nh * 8 + q * 2))      = make_uint2(h0w, h1w);
                *((uint2_a*)(hrow + 16 + nh * 8 + q * 2)) = make_uint2(l0w, l1w);
            }
            const v8s bH = __builtin_bit_cast(v8s, *((const uint4_a*)(hrow + q * 4)));
            const v8s bL = __builtin_bit_cast(v8s, *((const uint4_a*)(hrow + 16 + q * 4)));

            #pragma unroll
            for (int nt = 0; nt < 4; ++nt) {
                const v8s a_h = __builtin_bit_cast(v8s, w1LDS[tOff + (nt * 2 + ks) * 64 + lane]);
                const v8s a_l = __builtin_bit_cast(v8s, w1LDS[tOff + 512 + (nt * 2 + ks) * 64 + lane]);
                v4f c = acc1[nt];
                c = __builtin_amdgcn_mfma_f32_16x16x32_bf16(a_l, bH, c, 0, 0, 0);
                c = __builtin_amdgcn_mfma_f32_16x16x32_bf16(a_h, bL, c, 0, 0, 0);
                c = __builtin_amdgcn_mfma_f32_16x16x32_bf16(a_h, bH, c, 0, 0, 0);
                acc1[nt] = c;
            }
        }

        // ---- L2 (64->3) in VALU: W2 direct from global (768 B, L1-hot) ----
        float o0 = 0.f, o1 = 0.f, o2 = 0.f;
        #pragma unroll
        for (int nt = 0; nt < 4; ++nt) {
            const int n0 = nt * 16 + q * 4;
            const float4 g0 = *((const float4*)(W2 + n0 * 3 + tOff));
            const float4 g1 = *((const float4*)(W2 + n0 * 3 + tOff + 4));
            const float4 g2 = *((const float4*)(W2 + n0 * 3 + tOff + 8));
            const float h0r = fmaxf(acc1[nt][0], 0.f), h1r = fmaxf(acc1[nt][1], 0.f);
            const float h2r = fmaxf(acc1[nt][2], 0.f), h3r = fmaxf(acc1[nt][3], 0.f);
            o0 = fmaf(h0r, g0.x, fmaf(h1r, g0.w, fmaf(h2r, g1.z, fmaf(h3r, g2.y, o0))));
            o1 = fmaf(h0r, g0.y, fmaf(h1r, g1.x, fmaf(h2r, g1.w, fmaf(h3r, g2.z, o1))));
            o2 = fmaf(h0r, g0.z, fmaf(h1r, g1.y, fmaf(h2r, g2.x, fmaf(h3r, g2.w, o2))));
        }
        o0 += __shfl_xor(o0, 16); o0 += __shfl_xor(o0, 32);
        o1 += __shfl_xor(o1, 16); o1 += __shfl_xor(o1, 32);
        o2 += __shfl_xor(o2, 16); o2 += __shfl_xor(o2, 32);

        if (lane < 16) {
            const int p2 = blockBase + wave * 64 + t * 16 + lane;
            out[p2] = o0;
            out[NPTS + p2] = o1;
            out[2 * NPTS + p2] = o2;
        }

        // rotate prefetched e-frags into place for the next tile
        eHc = eHn;
        eLc = eLn;
    }
}

extern "C" void kernel_launch(void* const* d_in, const int* in_sizes, int n_in,
                              void* d_out, int out_size, void* d_ws, size_t ws_size,
                              hipStream_t stream) {
    const float* xy     = (const float*)d_in[0];
    const float* tables = (const float*)d_in[1];
    const float* W0     = (const float*)d_in[2];
    const float* W1     = (const float*)d_in[3];
    const float* W2     = (const float*)d_in[4];
    float* out = (float*)d_out;
    uint4* ws  = (uint4*)d_ws;   // 1536 x 16B = 24 KB

    hipLaunchKernelGGL(prep_weights, dim3(3), dim3(256), 0, stream, W0, W1, ws);
    hipLaunchKernelGGL(ngp_mfma, dim3(NPTS / 256), dim3(256), 0, stream,
                       xy, tables, W2, ws, out);
}